// Round 4
// baseline (2188.508 us; speedup 1.0000x reference)
//
#include <hip/hip_runtime.h>
#include <hip/hip_bf16.h>

// Problem constants (Cross_WindowAttention): B=2048, N=64, C=512, H=16, hd=32
#define BATCH   2048
#define SEQ     64
#define CH      512
#define NHEADS  16
#define HDIM    32
#define QKVELEM ((size_t)BATCH*NHEADS*SEQ*HDIM)   // 67108864 elements per tensor

typedef __attribute__((ext_vector_type(8))) short bfrag8;   // 8 bf16 (4 VGPRs)
typedef __attribute__((ext_vector_type(4))) float accf4;    // MFMA accumulator

__device__ __forceinline__ short f2bf(float f) {
    union { __hip_bfloat16 h; short s; } u;
    u.h = __float2bfloat16(f);
    return u.s;
}
__device__ __forceinline__ float bf2f(short s) {
    union { short s; __hip_bfloat16 h; } u;
    u.s = s;
    return __bfloat162float(u.h);
}

// async global->LDS, 16B/lane; LDS dest must be wave-uniform base + lane*16.
// All call sites below are lane-linear by construction (verified: offsets
// decompose as wave_base + lane*16 bytes).
#define GLL16(gp, lp) __builtin_amdgcn_global_load_lds( \
    (const __attribute__((address_space(1))) void*)(gp), \
    (__attribute__((address_space(3))) void*)(lp), 16, 0, 0)

// ---------------------------------------------------------------------------
// Weight transpose+convert: out[n][k] = (k < K_in) ? in[k][n0+n] : 0   (bf16)
// ---------------------------------------------------------------------------
__global__ void transp_conv(const float* __restrict__ in, short* __restrict__ out,
                            int K_in, int N_in, int n0, int Kpad) {
    __shared__ float tile[32][33];
    const int tx = threadIdx.x & 31, ty = threadIdx.x >> 5;
    const int nb = blockIdx.x * 32, kb = blockIdx.y * 32;
#pragma unroll
    for (int p = 0; p < 4; ++p) {
        int k = kb + ty + p * 8;
        tile[ty + p * 8][tx] = (k < K_in) ? in[(size_t)k * N_in + n0 + nb + tx] : 0.f;
    }
    __syncthreads();
#pragma unroll
    for (int p = 0; p < 4; ++p) {
        int nl = ty + p * 8;
        out[(size_t)(nb + nl) * Kpad + kb + tx] = f2bf(tile[tx][nl]);
    }
}

// ---------------------------------------------------------------------------
// rpb[h][n][m] = bias_table[rel_index[n][m]][h]   (fp32, added exactly)
// ---------------------------------------------------------------------------
__global__ void rpb_kernel(const float* __restrict__ bt, const int* __restrict__ ri,
                           float* __restrict__ rpb) {
    int nm = blockIdx.x * 256 + threadIdx.x;   // 0..4095
    int idx = ri[nm];
#pragma unroll
    for (int h = 0; h < NHEADS; ++h)
        rpb[h * 4096 + nm] = bt[idx * NHEADS + h];
}

// ---------------------------------------------------------------------------
// MFMA GEMM: C[M,N] = A[M,K] @ Bt[N,K]^T, 128x128 tile, BK=32, 4 waves (2x2),
// 4x4 fragments of mfma_f32_16x16x32_bf16. Double-buffered LDS; B (and bf16 A)
// via global_load_lds; fp32 A reg-staged + converted (loads issued early,
// ds_write after MFMA -- T14 ordering).
// EPI 0: qkv1 scatter->Q(scaled)/K/V bf16. EPI 1: qkv2 RMW-add into K/V bf16.
// EPI 2: proj -> fp32 out.
// Fragment conventions (m89/m91-verified): A/B frag: lane&15=row(col),
// k=(lane>>4)*8..+8 contiguous; C/D: col=lane&15, row=(lane>>4)*4+reg.
// ---------------------------------------------------------------------------
template<int KSTEPS, int NT, bool ABF16, bool TAIL, int EPI>
__launch_bounds__(256, 3)
__global__ void mfma_gemm(const float* __restrict__ Af, const short* __restrict__ Ab,
                          const short* __restrict__ Bt, const float* __restrict__ bias,
                          short* __restrict__ S0, short* __restrict__ S1,
                          short* __restrict__ S2, float* __restrict__ F0,
                          int lda, int ldb) {
    __shared__ short As[2][128 * 32];
    __shared__ short Bs[2][128 * 32];

    const int tid  = threadIdx.x;
    const int lane = tid & 63;
    const int wv   = tid >> 6;
    const int wr   = wv >> 1, wc = wv & 1;

    // bijective XCD-chunk swizzle (all grids %8==0), n-fastest decode
    const int nwg = gridDim.x;
    const int bid = blockIdx.x;
    const int wg  = (bid & 7) * (nwg >> 3) + (bid >> 3);
    const int mt  = wg / NT, nt = wg - mt * NT;
    const int m0  = mt * 128, n0 = nt * 128;

    accf4 acc[4][4] = {};

    const int brow = tid >> 2;           // staging: 64 rows per issue
    const int bcol = (tid & 3) * 8;      // 8 shorts = 16B within a 64B row
    const int arow = tid >> 1;           // fp32-A: 2 threads/row
    const int acb  = (tid & 1) * 16;

    float av[16];

    auto stageB = [&](int buf, int k0) {
#pragma unroll
        for (int i = 0; i < 2; ++i) {
            int row = i * 64 + brow;
            GLL16(Bt + (size_t)(n0 + row) * ldb + k0 + bcol,
                  &Bs[buf][row * 32 + bcol]);
        }
    };
    auto stageAb = [&](int buf, int k0) {
#pragma unroll
        for (int i = 0; i < 2; ++i) {
            int row = i * 64 + brow;
            GLL16(Ab + (size_t)(m0 + row) * lda + k0 + bcol,
                  &As[buf][row * 32 + bcol]);
        }
    };
    auto loadA = [&](int k0, bool tail) {
        const float* ap = Af + (size_t)(m0 + arow) * lda + k0 + acb;
        if (!tail) {
#pragma unroll
            for (int q = 0; q < 4; ++q) {
                float4 v = *(const float4*)(ap + q * 4);
                av[q * 4 + 0] = v.x; av[q * 4 + 1] = v.y;
                av[q * 4 + 2] = v.z; av[q * 4 + 3] = v.w;
            }
        } else {
#pragma unroll
            for (int e = 0; e < 16; ++e) {
                int kk = k0 + acb + e;
                av[e] = (kk < 1000) ? ap[e] : 0.f;   // K=1000 tail pad
            }
        }
    };
    auto writeA = [&](int buf) {
        short tmp[16];
#pragma unroll
        for (int e = 0; e < 16; ++e) tmp[e] = f2bf(av[e]);
        bfrag8 p0, p1;
#pragma unroll
        for (int e = 0; e < 8; ++e) { p0[e] = tmp[e]; p1[e] = tmp[8 + e]; }
        *(bfrag8*)&As[buf][arow * 32 + acb]     = p0;
        *(bfrag8*)&As[buf][arow * 32 + acb + 8] = p1;
    };
    auto compute = [&](int buf) {
        const int ro = (lane & 15) * 32 + (lane >> 4) * 8;
        bfrag8 afr[4], bfr[4];
#pragma unroll
        for (int m = 0; m < 4; ++m)
            afr[m] = *(const bfrag8*)&As[buf][(wr * 64 + m * 16) * 32 + ro];
#pragma unroll
        for (int n = 0; n < 4; ++n)
            bfr[n] = *(const bfrag8*)&Bs[buf][(wc * 64 + n * 16) * 32 + ro];
#pragma unroll
        for (int m = 0; m < 4; ++m)
#pragma unroll
            for (int n = 0; n < 4; ++n)
                acc[m][n] = __builtin_amdgcn_mfma_f32_16x16x32_bf16(
                    afr[m], bfr[n], acc[m][n], 0, 0, 0);
    };

    // prologue
    if (ABF16) stageAb(0, 0);
    else { loadA(0, TAIL && KSTEPS == 1); writeA(0); }
    stageB(0, 0);
    __syncthreads();

    int buf = 0;
#pragma unroll 1
    for (int t = 0; t < KSTEPS - 1; ++t) {
        const int k1 = (t + 1) * 32;
        const bool tail = TAIL && (t + 1 == KSTEPS - 1);
        if (ABF16) stageAb(buf ^ 1, k1);
        else loadA(k1, tail);                 // issue global loads early
        stageB(buf ^ 1, k1);
        compute(buf);                         // MFMA hides load latency
        if (!ABF16) writeA(buf ^ 1);          // ds_write after compute
        __syncthreads();
        buf ^= 1;
    }
    compute(buf);

    const float scale = 0.17677669529663687f;  // hd^-0.5
#pragma unroll
    for (int n = 0; n < 4; ++n) {
        const int c = n0 + wc * 64 + n * 16 + (lane & 15);
        if (EPI == 0) {
            float bv = bias[c];
            short* dst; int hh, d; float sc = 1.f;
            if (c < 512)       { dst = S0; hh = c >> 5;         d = c & 31; sc = scale; }
            else if (c < 1024) { dst = S1; hh = (c - 512) >> 5; d = c & 31; }
            else               { dst = S2; hh = (c - 1024) >> 5; d = c & 31; }
#pragma unroll
            for (int m = 0; m < 4; ++m) {
                int Rb = m0 + wr * 64 + m * 16 + (lane >> 4) * 4;
#pragma unroll
                for (int r = 0; r < 4; ++r) {
                    int R = Rb + r, bb = R >> 6, nn = R & 63;
                    size_t idx = ((((size_t)bb * NHEADS) + hh) * SEQ + nn) * HDIM + d;
                    dst[idx] = f2bf((acc[m][n][r] + bv) * sc);
                }
            }
        } else if (EPI == 1) {
            float bv = bias[512 + c];
            short* dst = (c < 512) ? S0 : S1;
            int hh = (c & 511) >> 5, d = c & 31;
#pragma unroll
            for (int m = 0; m < 4; ++m) {
                int Rb = m0 + wr * 64 + m * 16 + (lane >> 4) * 4;
#pragma unroll
                for (int r = 0; r < 4; ++r) {
                    int R = Rb + r, bb = R >> 6, nn = R & 63;
                    size_t idx = ((((size_t)bb * NHEADS) + hh) * SEQ + nn) * HDIM + d;
                    dst[idx] = f2bf(bf2f(dst[idx]) + acc[m][n][r] + bv);
                }
            }
        } else {
            float bv = bias[c];
#pragma unroll
            for (int m = 0; m < 4; ++m) {
                int Rb = m0 + wr * 64 + m * 16 + (lane >> 4) * 4;
#pragma unroll
                for (int r = 0; r < 4; ++r)
                    F0[(size_t)(Rb + r) * CH + c] = acc[m][n][r] + bv;
            }
        }
    }
}

// ---------------------------------------------------------------------------
// MFMA attention: one block per (b,h), 4 waves; wave w owns S rows [16w,16w+16).
// S = Q.K^T via mfma(Q-frag, K-frag) (K rows = S cols, same B^T convention as
// GEMM). D-layout: col(m)=lane&15 within 16-chunk, row=(lane>>4)*4+reg.
// Softmax row lives inside one 16-lane group -> shfl_xor{1,2,4,8} butterfly.
// Unnormalized P -> LDS (pad-68 stride, conflict-free group banks), PV MFMA
// with Vt[d][m] as B^T, scale by inv[reg] at writeout (row<->(g,reg) mapping
// identical for S and O, so inv never leaves the lane).
// ---------------------------------------------------------------------------
__launch_bounds__(256, 2)
__global__ void attn_mfma(const short* __restrict__ Qb, const short* __restrict__ Kb,
                          const short* __restrict__ Vb, const float* __restrict__ rpb,
                          const float* __restrict__ mask, short* __restrict__ AO) {
    __shared__ short Qs[64 * 32];
    __shared__ short Ks[64 * 32];
    __shared__ short Vt[32 * 68];   // Vt[d][m], stride 68 (pad)
    __shared__ short Ps[64 * 68];   // P[r][m], stride 68

    const int bh = blockIdx.x;
    const int b = bh >> 4, h = bh & 15;
    const int tid  = threadIdx.x;
    const int lane = tid & 63;
    const int w    = tid >> 6;
    const int g    = lane >> 4;
    const int c15  = lane & 15;

    const short* qp = Qb + (size_t)bh * 2048;
    const short* kp = Kb + (size_t)bh * 2048;
    const short* vp = Vb + (size_t)bh * 2048;

    GLL16(qp + tid * 8, &Qs[tid * 8]);      // lane-linear: tid*16B
    GLL16(kp + tid * 8, &Ks[tid * 8]);
    {   // V transpose into Vt[d][m]
        short4 v0 = *(const short4*)(vp + tid * 8);
        short4 v1 = *(const short4*)(vp + tid * 8 + 4);
        int m = tid >> 2, d0 = (tid & 3) * 8;
        Vt[(d0 + 0) * 68 + m] = v0.x; Vt[(d0 + 1) * 68 + m] = v0.y;
        Vt[(d0 + 2) * 68 + m] = v0.z; Vt[(d0 + 3) * 68 + m] = v0.w;
        Vt[(d0 + 4) * 68 + m] = v1.x; Vt[(d0 + 5) * 68 + m] = v1.y;
        Vt[(d0 + 6) * 68 + m] = v1.z; Vt[(d0 + 7) * 68 + m] = v1.w;
    }
    __syncthreads();   // drains GLL16 (vmcnt) + Vt writes

    // ---- QK^T: wave w rows [16w,16w+16), all 64 cols (4 fragments) ----
    const int ro = c15 * 32 + g * 8;
    bfrag8 aq = *(const bfrag8*)&Qs[w * 512 + ro];
    accf4 accS[4] = {};
#pragma unroll
    for (int n = 0; n < 4; ++n) {
        bfrag8 bk = *(const bfrag8*)&Ks[n * 512 + ro];
        accS[n] = __builtin_amdgcn_mfma_f32_16x16x32_bf16(aq, bk, accS[n], 0, 0, 0);
    }

    // ---- + rpb + mask (fp32, exact), softmax in-register ----
    const float* rpb_b = rpb + h * 4096;
    const float* msk_b = mask + (size_t)(b & 63) * 4096;
    float p[4][4];      // [n][reg]
    float inv[4];
#pragma unroll
    for (int reg = 0; reg < 4; ++reg) {
        const int r = w * 16 + g * 4 + reg;
        float sv[4];
#pragma unroll
        for (int n = 0; n < 4; ++n) {
            int m = n * 16 + c15;
            sv[n] = accS[n][reg] + rpb_b[r * 64 + m] + msk_b[r * 64 + m];
        }
        float mx = fmaxf(fmaxf(sv[0], sv[1]), fmaxf(sv[2], sv[3]));
#pragma unroll
        for (int mk = 1; mk <= 8; mk <<= 1) mx = fmaxf(mx, __shfl_xor(mx, mk));
        float sm = 0.f;
#pragma unroll
        for (int n = 0; n < 4; ++n) { p[n][reg] = __expf(sv[n] - mx); sm += p[n][reg]; }
#pragma unroll
        for (int mk = 1; mk <= 8; mk <<= 1) sm += __shfl_xor(sm, mk);
        inv[reg] = 1.f / sm;
    }

    // ---- unnormalized P -> LDS (wave-private 16-row band, no barrier) ----
#pragma unroll
    for (int reg = 0; reg < 4; ++reg) {
        const int rl = w * 16 + g * 4 + reg;
#pragma unroll
        for (int n = 0; n < 4; ++n)
            Ps[rl * 68 + n * 16 + c15] = f2bf(p[n][reg]);
    }

    // ---- PV: O[r][d] = sum_m P[r][m] Vt[d][m] ----
    accf4 accO[2] = {};
#pragma unroll
    for (int kc = 0; kc < 2; ++kc) {
        const int km = kc * 32;
        int po = (w * 16 + c15) * 68 + km + g * 8;
        short4 plo = *(const short4*)&Ps[po];
        short4 phi = *(const short4*)&Ps[po + 4];
        bfrag8 pa;
        pa[0] = plo.x; pa[1] = plo.y; pa[2] = plo.z; pa[3] = plo.w;
        pa[4] = phi.x; pa[5] = phi.y; pa[6] = phi.z; pa[7] = phi.w;
#pragma unroll
        for (int nc = 0; nc < 2; ++nc) {
            int vo = (nc * 16 + c15) * 68 + km + g * 8;
            short4 vlo = *(const short4*)&Vt[vo];
            short4 vhi = *(const short4*)&Vt[vo + 4];
            bfrag8 vbf;
            vbf[0] = vlo.x; vbf[1] = vlo.y; vbf[2] = vlo.z; vbf[3] = vlo.w;
            vbf[4] = vhi.x; vbf[5] = vhi.y; vbf[6] = vhi.z; vbf[7] = vhi.w;
            accO[nc] = __builtin_amdgcn_mfma_f32_16x16x32_bf16(pa, vbf, accO[nc], 0, 0, 0);
        }
    }

    // ---- scale + store: AO[b, 16w + 4g + reg, h*32 + 16nc + c15] ----
    short* ao = AO + ((size_t)(b * 64 + w * 16)) * 512 + h * 32;
#pragma unroll
    for (int reg = 0; reg < 4; ++reg) {
        const int rl = g * 4 + reg;
#pragma unroll
        for (int nc = 0; nc < 2; ++nc)
            ao[(size_t)rl * 512 + nc * 16 + c15] = f2bf(accO[nc][reg] * inv[reg]);
    }
}

// ---------------------------------------------------------------------------
extern "C" void kernel_launch(void* const* d_in, const int* in_sizes, int n_in,
                              void* d_out, int out_size, void* d_ws, size_t ws_size,
                              hipStream_t stream) {
    const float* x    = (const float*)d_in[0];
    const float* y    = (const float*)d_in[1];
    const float* mask = (const float*)d_in[2];
    const float* w1   = (const float*)d_in[3];
    const float* b1   = (const float*)d_in[4];
    const float* w2   = (const float*)d_in[5];
    const float* b2   = (const float*)d_in[6];
    const float* bt   = (const float*)d_in[7];
    const int*   ri   = (const int*)d_in[8];
    const float* wp   = (const float*)d_in[9];
    const float* bp   = (const float*)d_in[10];
    float* out = (float*)d_out;

    short* Qb = (short*)d_ws;
    short* Kb = Qb + QKVELEM;
    short* Vb = Kb + QKVELEM;
    short* AO = Vb + QKVELEM;                 // 4 x 134 MB bf16
    float* RPB = (float*)(AO + QKVELEM);      // 256 KB fp32
    short* w1t = (short*)(RPB + 65536);       // [1536][512]
    short* w2t = w1t + (size_t)1536 * 512;    // [1024][1024] (K 1000->1024, zero-pad)
    short* wpt = w2t + (size_t)1024 * 1024;   // [512][512]
    // total ~541 MB

    rpb_kernel<<<16, 256, 0, stream>>>(bt, ri, RPB);
    transp_conv<<<dim3(48, 16), 256, 0, stream>>>(w1, w1t, 512, 1536, 0, 512);
    transp_conv<<<dim3(32, 32), 256, 0, stream>>>(w2, w2t, 1000, 1536, 512, 1024);
    transp_conv<<<dim3(16, 16), 256, 0, stream>>>(wp, wpt, 512, 512, 0, 512);

    mfma_gemm<16, 12, false, false, 0><<<12288, 256, 0, stream>>>(
        x, nullptr, w1t, b1, Qb, Kb, Vb, nullptr, 512, 512);
    mfma_gemm<32, 8, false, true, 1><<<8192, 256, 0, stream>>>(
        y, nullptr, w2t, b2, Kb, Vb, nullptr, nullptr, 1000, 1024);
    attn_mfma<<<32768, 256, 0, stream>>>(Qb, Kb, Vb, RPB, mask, AO);
    mfma_gemm<16, 4, true, false, 2><<<4096, 256, 0, stream>>>(
        nullptr, AO, wpt, bp, nullptr, nullptr, nullptr, out, 512, 512);
}